// Round 6
// baseline (253.187 us; speedup 1.0000x reference)
//
#include <hip/hip_runtime.h>
#include <hip/hip_bf16.h>

// FourierKANLayer: out[n,o] = bias[o] + sum_{i,b} coeffs[o,i,b] * basis[n,i,b]
// basis = [1, sin(m*pi*x) m=1..32, cos(m*pi*x) m=1..32] per (n,i).
//
// R6 design: bf16 MFMA 32x32x16. Wave = 64 rows x 64 cols x i-QUARTER:
// block 256 thr = 4 waves splitting K 4 ways (no duplicated recurrence/cvt,
// state = 80 VGPR -> real 2 waves/SIMD). Each A-frag feeds 2 MFMAs (2 col
// frags), each B-frag ds_read feeds 2 MFMAs (2 row tiles). fp32 Chebyshev
// (v' = T*v - v_prev, T=2cos(pi*x)), mode-pair unroll. K-partials reduced via
// balanced quadrant-exchange epilogue in LDS. 2 x 32 KB staging buffers,
// global_load_lds(16B). Grid 1024 (64 rows/block), 2 blocks/CU.

typedef __bf16 bf16x8 __attribute__((ext_vector_type(8)));
typedef float  f32x4  __attribute__((ext_vector_type(4)));
typedef float  f32x16 __attribute__((ext_vector_type(16)));

#define PI_F 3.14159265358979323846f

// ---------------------------------------------------------------------------
// Repack coeffs [64][64][65] fp32 -> Bp bf16 in 32x32x16 B-fragment order.
// One thread per input element (coalesced read, scattered 2B write):
//   b==0 -> atomicAdd into bias2sum[o] (pre-zeroed via hipMemsetAsync)
//   else  m=(b-1)&31, sc=(b>=33), frag=(m*8+kc)*2+cc, lane=kq*32+(o&31),
//         t=2*(i&3)+sc;  Bp[frag*512 + lane*8 + t] = bf16(v)
// Bp total: 512 frags * 512 elems * 2 B = 512 KB. bias2sum AFTER it.
// ---------------------------------------------------------------------------
__global__ __launch_bounds__(256) void fkan_repack(
    const float* __restrict__ coeffs, __bf16* __restrict__ Bp,
    float* __restrict__ bias2sum) {
  int gid = blockIdx.x * 256 + threadIdx.x;   // 0 .. 266239
  if (gid >= 64 * 64 * 65) return;
  float v = coeffs[gid];
  int b  = gid % 65;
  int oi = gid / 65;
  int i = oi & 63;
  int o = oi >> 6;
  if (b == 0) {
    atomicAdd(&bias2sum[o], v);
    return;
  }
  int m  = (b - 1) & 31;
  int sc = (b >= 33) ? 1 : 0;
  int kc = i >> 3;
  int kq = (i >> 2) & 1;
  int cc = o >> 5;
  int frag = (m * 8 + kc) * 2 + cc;
  int lane = kq * 32 + (o & 31);
  int t = 2 * (i & 3) + sc;
  Bp[frag * 512 + lane * 8 + t] = (__bf16)v;
}

// ---------------------------------------------------------------------------
// Stage one mode-PAIR (32 KB) into LDS: 256 threads x 16 B x 8 rounds.
// ---------------------------------------------------------------------------
__device__ __forceinline__ void stage_pair(const __bf16* __restrict__ Bp,
                                           __bf16* dst, int pair, int wave,
                                           int lane) {
  const char* g = (const char*)Bp + (size_t)pair * 32768 + wave * 1024 + lane * 16;
  char* l = (char*)dst + wave * 1024;
  #pragma unroll
  for (int r = 0; r < 8; ++r) {
    __builtin_amdgcn_global_load_lds(
        (const __attribute__((address_space(1))) void*)(g + r * 4096),
        (__attribute__((address_space(3))) void*)(l + r * 4096), 16, 0, 0);
  }
}

// ---------------------------------------------------------------------------
// Main kernel: 256 threads = 4 waves; block = 64 rows x 64 cols, full K.
// Wave w = i-quarter: i in [w*16, w*16+16). All waves share the 64 rows and
// 64 cols. Lane: cl=lane&31 (row in tile), kq=lane>>5 (K-quarter of frag).
// Lane instance p = t*8 + kc*4 + e <-> (row = base+t*32+cl,
//   i = w*16 + kc*8 + kq*4 + e), kc in [0,2), e in [0,4).
// Per mode: 2 kc x 2 tiles x 2 cols = 8 MFMA; 4 B-frag ds_read_b128 (each
// feeds 2 row-tiles); 4 A-builds (each feeds 2 col MFMAs); 32 fma advance.
// Epilogue: quadrant exchange — wave w owns output quadrant (t=w>>1,cc=w&1),
// writes its other 3 quadrant-accs to LDS, sums 3 partials for its own.
// ---------------------------------------------------------------------------
__global__ __launch_bounds__(256, 2) void fkan_main(
    const float* __restrict__ x, const __bf16* __restrict__ Bp,
    const float* __restrict__ bias, const float* __restrict__ bias2sum,
    float* __restrict__ out) {
  __shared__ __bf16 Bs[2][16384];   // 2 x 32 KB (one mode-pair each)

  int tid  = threadIdx.x;
  int wave = tid >> 6;
  int lane = tid & 63;
  int kq   = lane >> 5;
  int cl   = lane & 31;
  int rowbase = blockIdx.x * 64;

  // --- init: Chebyshev state for 16 (row,i) instances ----------------------
  float sC[16], cC[16], sP[16], cP[16], Tch[16];
  #pragma unroll
  for (int t = 0; t < 2; ++t) {
    const float* xrow =
        x + (size_t)(rowbase + t * 32 + cl) * 64 + wave * 16 + kq * 4;
    #pragma unroll
    for (int kc = 0; kc < 2; ++kc) {
      f32x4 v = *(const f32x4*)(xrow + kc * 8);
      #pragma unroll
      for (int e = 0; e < 4; ++e) {
        int p = t * 8 + kc * 4 + e;
        float ss, cs;
        __sincosf(PI_F * v[e], &ss, &cs);
        sC[p] = ss;  cC[p] = cs;
        sP[p] = 0.f; cP[p] = 1.f;
        Tch[p] = 2.0f * cs;
      }
    }
  }

  f32x16 acc[2][2];                  // [row-tile][col-frag]
  #pragma unroll
  for (int t = 0; t < 2; ++t)
    #pragma unroll
    for (int cc = 0; cc < 2; ++cc)
      #pragma unroll
      for (int r = 0; r < 16; ++r) acc[t][cc][r] = 0.f;

  stage_pair(Bp, &Bs[0][0], 0, wave, lane);
  __syncthreads();

  // wave-uniform LDS base for this wave's K-quarter: frags (wave*2+kc)*2+cc
  int ldsbase = wave * 2048 + lane * 8;   // elements

  // --- mode-pair loop: pair p covers freqs 2p+1 (cur) and 2p+2 (prev) ------
  for (int p = 0; p < 16; ++p) {
    int buf = p & 1;
    if (p < 15) stage_pair(Bp, &Bs[buf ^ 1][0], p + 1, wave, lane);
    const __bf16* Bb = &Bs[buf][ldsbase];

    // ---- first mode of pair: A from (sC,cC), B at offset 0
    #pragma unroll
    for (int kc = 0; kc < 2; ++kc) {
      bf16x8 af[2];
      #pragma unroll
      for (int t = 0; t < 2; ++t)
        #pragma unroll
        for (int e = 0; e < 4; ++e) {
          af[t][2 * e]     = (__bf16)sC[t * 8 + kc * 4 + e];
          af[t][2 * e + 1] = (__bf16)cC[t * 8 + kc * 4 + e];
        }
      #pragma unroll
      for (int cc = 0; cc < 2; ++cc) {
        bf16x8 bfr = *(const bf16x8*)(Bb + (kc * 2 + cc) * 512);
        #pragma unroll
        for (int t = 0; t < 2; ++t)
          acc[t][cc] = __builtin_amdgcn_mfma_f32_32x32x16_bf16(af[t], bfr,
                                                               acc[t][cc],
                                                               0, 0, 0);
      }
    }
    #pragma unroll
    for (int q = 0; q < 16; ++q) {    // prev <- freq 2p+2
      sP[q] = fmaf(Tch[q], sC[q], -sP[q]);
      cP[q] = fmaf(Tch[q], cC[q], -cP[q]);
    }

    // ---- second mode of pair: A from (sP,cP), B at +8192 elements
    #pragma unroll
    for (int kc = 0; kc < 2; ++kc) {
      bf16x8 af[2];
      #pragma unroll
      for (int t = 0; t < 2; ++t)
        #pragma unroll
        for (int e = 0; e < 4; ++e) {
          af[t][2 * e]     = (__bf16)sP[t * 8 + kc * 4 + e];
          af[t][2 * e + 1] = (__bf16)cP[t * 8 + kc * 4 + e];
        }
      #pragma unroll
      for (int cc = 0; cc < 2; ++cc) {
        bf16x8 bfr = *(const bf16x8*)(Bb + 8192 + (kc * 2 + cc) * 512);
        #pragma unroll
        for (int t = 0; t < 2; ++t)
          acc[t][cc] = __builtin_amdgcn_mfma_f32_32x32x16_bf16(af[t], bfr,
                                                               acc[t][cc],
                                                               0, 0, 0);
      }
    }
    #pragma unroll
    for (int q = 0; q < 16; ++q) {    // cur <- freq 2p+3
      sC[q] = fmaf(Tch[q], sP[q], -sC[q]);
      cC[q] = fmaf(Tch[q], cP[q], -cC[q]);
    }
    __syncthreads();
  }

  // --- epilogue: quadrant exchange. Wave w owns quadrant q=w (t=q>>1,cc=q&1).
  // LDS slot (q, contributor w): floats at (q*4+w)*1024 + lane*16 + rq*4.
  float* LX = (float*)&Bs[0][0];     // 64 KB scratch
  #pragma unroll
  for (int q = 0; q < 4; ++q) {
    if (q == wave) continue;
    float* dst = LX + (q * 4 + wave) * 1024 + lane * 16;
    #pragma unroll
    for (int rq = 0; rq < 4; ++rq) {
      f32x4 vv;
      #pragma unroll
      for (int e = 0; e < 4; ++e) vv[e] = acc[q >> 1][q & 1][rq * 4 + e];
      *(f32x4*)(dst + rq * 4) = vv;
    }
  }
  __syncthreads();

  int t_own = wave >> 1, c_own = wave & 1;
  f32x16 sum = acc[t_own][c_own];
  #pragma unroll
  for (int w2 = 0; w2 < 4; ++w2) {
    if (w2 == wave) continue;
    const float* src = LX + (wave * 4 + w2) * 1024 + lane * 16;
    #pragma unroll
    for (int rq = 0; rq < 4; ++rq) {
      f32x4 vv = *(const f32x4*)(src + rq * 4);
      #pragma unroll
      for (int e = 0; e < 4; ++e) sum[rq * 4 + e] += vv[e];
    }
  }

  int col = c_own * 32 + cl;
  float bv = bias[col] + bias2sum[col];
  float* orow = out + (size_t)(rowbase + t_own * 32) * 64;
  #pragma unroll
  for (int r = 0; r < 16; ++r) {
    int ro = (r & 3) + 8 * (r >> 2) + 4 * kq;
    orow[(size_t)ro * 64 + col] = sum[r] + bv;
  }
}

extern "C" void kernel_launch(void* const* d_in, const int* in_sizes, int n_in,
                              void* d_out, int out_size, void* d_ws, size_t ws_size,
                              hipStream_t stream) {
  const float* x      = (const float*)d_in[0];   // [65536, 64]
  const float* coeffs = (const float*)d_in[1];   // [64, 64, 65]
  const float* bias   = (const float*)d_in[2];   // [64]
  float* out = (float*)d_out;

  __bf16* Bp      = (__bf16*)d_ws;               // 512 KB (512 frags * 1 KB)
  float* bias2sum = (float*)((char*)d_ws + 512 * 1024);  // AFTER Bp

  int n_rows = in_sizes[0] / 64;                 // 65536

  hipMemsetAsync(bias2sum, 0, 64 * sizeof(float), stream);
  fkan_repack<<<(64 * 64 * 65 + 255) / 256, 256, 0, stream>>>(coeffs, Bp,
                                                              bias2sum);
  fkan_main<<<n_rows / 64, 256, 0, stream>>>(x, Bp, bias, bias2sum, out);
}

// Round 7
// 135.453 us; speedup vs baseline: 1.8692x; 1.8692x over previous
//
#include <hip/hip_runtime.h>
#include <hip/hip_bf16.h>

// FourierKANLayer: out[n,o] = bias[o] + sum_{i,b} coeffs[o,i,b] * basis[n,i,b]
// basis = [1, sin(m*pi*x) m=1..32, cos(m*pi*x) m=1..32] per (n,i).
//
// R7 = R6 structure with the scratch-spill bug fixed:
//  - NO runtime indexing of acc[][] (wave-uniform branch with compile-time
//    register indices in each arm) -> acc lives in VGPRs/AGPRs.
//  - Conflict-free epilogue exchange layout (r*64 + lane, lane-stride 1).
// Wave = 64 rows x 64 cols x i-QUARTER (K split 4 ways across waves):
// no duplicated recurrence/cvt; each A-frag feeds 2 MFMAs, each B-frag
// ds_read_b128 feeds 2 MFMAs. fp32 Chebyshev recurrence, mode-pair unroll.
// 2 x 32 KB staging buffers, global_load_lds(16B). Grid 1024, 2 blocks/CU.

typedef __bf16 bf16x8 __attribute__((ext_vector_type(8)));
typedef float  f32x4  __attribute__((ext_vector_type(4)));
typedef float  f32x16 __attribute__((ext_vector_type(16)));

#define PI_F 3.14159265358979323846f

// ---------------------------------------------------------------------------
// Repack coeffs [64][64][65] fp32 -> Bp bf16 in 32x32x16 B-fragment order.
//   b==0 -> atomicAdd into bias2sum[o] (pre-zeroed via hipMemsetAsync)
//   else  m=(b-1)&31, sc=(b>=33), frag=(m*8+kc)*2+cc, lane=kq*32+(o&31),
//         t=2*(i&3)+sc;  Bp[frag*512 + lane*8 + t] = bf16(v)
// Bp total: 512 KB. bias2sum placed AFTER it.
// ---------------------------------------------------------------------------
__global__ __launch_bounds__(256) void fkan_repack(
    const float* __restrict__ coeffs, __bf16* __restrict__ Bp,
    float* __restrict__ bias2sum) {
  int gid = blockIdx.x * 256 + threadIdx.x;
  if (gid >= 64 * 64 * 65) return;
  float v = coeffs[gid];
  int b  = gid % 65;
  int oi = gid / 65;
  int i = oi & 63;
  int o = oi >> 6;
  if (b == 0) {
    atomicAdd(&bias2sum[o], v);
    return;
  }
  int m  = (b - 1) & 31;
  int sc = (b >= 33) ? 1 : 0;
  int kc = i >> 3;
  int kq = (i >> 2) & 1;
  int cc = o >> 5;
  int frag = (m * 8 + kc) * 2 + cc;
  int lane = kq * 32 + (o & 31);
  int t = 2 * (i & 3) + sc;
  Bp[frag * 512 + lane * 8 + t] = (__bf16)v;
}

// ---------------------------------------------------------------------------
// Stage one mode-PAIR (32 KB) into LDS: 256 threads x 16 B x 8 rounds.
// ---------------------------------------------------------------------------
__device__ __forceinline__ void stage_pair(const __bf16* __restrict__ Bp,
                                           __bf16* dst, int pair, int wave,
                                           int lane) {
  const char* g = (const char*)Bp + (size_t)pair * 32768 + wave * 1024 + lane * 16;
  char* l = (char*)dst + wave * 1024;
  #pragma unroll
  for (int r = 0; r < 8; ++r) {
    __builtin_amdgcn_global_load_lds(
        (const __attribute__((address_space(1))) void*)(g + r * 4096),
        (__attribute__((address_space(3))) void*)(l + r * 4096), 16, 0, 0);
  }
}

// ---------------------------------------------------------------------------
// Main kernel: 256 threads = 4 waves; block = 64 rows x 64 cols, full K.
// Wave w = i-quarter: i in [w*16, w*16+16). Lane: cl=lane&31 (row in tile),
// kq=lane>>5 (K-quarter of frag). Lane instance p = t*8 + kc*4 + e <->
// (row = base+t*32+cl, i = w*16 + kc*8 + kq*4 + e), kc in [0,2), e in [0,4).
// Per mode: 8 MFMA; 4 B-frag ds_read_b128 (each feeds 2 row-tiles);
// 4 A-builds (each feeds 2 col MFMAs); 32 fma advance.
// Epilogue: quadrant exchange via LDS, conflict-free layout, NO dynamic
// register indexing (wave-uniform branch selects own quadrant).
// ---------------------------------------------------------------------------
__global__ __launch_bounds__(256, 2) void fkan_main(
    const float* __restrict__ x, const __bf16* __restrict__ Bp,
    const float* __restrict__ bias, const float* __restrict__ bias2sum,
    float* __restrict__ out) {
  __shared__ __bf16 Bs[2][16384];   // 2 x 32 KB (one mode-pair each)

  int tid  = threadIdx.x;
  int wave = tid >> 6;
  int lane = tid & 63;
  int kq   = lane >> 5;
  int cl   = lane & 31;
  int rowbase = blockIdx.x * 64;

  // --- init: Chebyshev state for 16 (row,i) instances ----------------------
  float sC[16], cC[16], sP[16], cP[16], Tch[16];
  #pragma unroll
  for (int t = 0; t < 2; ++t) {
    const float* xrow =
        x + (size_t)(rowbase + t * 32 + cl) * 64 + wave * 16 + kq * 4;
    #pragma unroll
    for (int kc = 0; kc < 2; ++kc) {
      f32x4 v = *(const f32x4*)(xrow + kc * 8);
      #pragma unroll
      for (int e = 0; e < 4; ++e) {
        int p = t * 8 + kc * 4 + e;
        float ss, cs;
        __sincosf(PI_F * v[e], &ss, &cs);
        sC[p] = ss;  cC[p] = cs;
        sP[p] = 0.f; cP[p] = 1.f;
        Tch[p] = 2.0f * cs;
      }
    }
  }

  f32x16 acc00, acc01, acc10, acc11;   // [row-tile][col-frag] as scalars
  #pragma unroll
  for (int r = 0; r < 16; ++r) {
    acc00[r] = 0.f; acc01[r] = 0.f; acc10[r] = 0.f; acc11[r] = 0.f;
  }

  stage_pair(Bp, &Bs[0][0], 0, wave, lane);
  __syncthreads();

  int ldsbase = wave * 2048 + lane * 8;   // elements

  // --- mode-pair loop: pair p covers freqs 2p+1 (cur) and 2p+2 (prev) ------
  for (int p = 0; p < 16; ++p) {
    int buf = p & 1;
    if (p < 15) stage_pair(Bp, &Bs[buf ^ 1][0], p + 1, wave, lane);
    const __bf16* Bb = &Bs[buf][ldsbase];

    // ---- first mode of pair: A from (sC,cC), B at offset 0
    #pragma unroll
    for (int kc = 0; kc < 2; ++kc) {
      bf16x8 af0, af1;
      #pragma unroll
      for (int e = 0; e < 4; ++e) {
        af0[2 * e]     = (__bf16)sC[kc * 4 + e];
        af0[2 * e + 1] = (__bf16)cC[kc * 4 + e];
        af1[2 * e]     = (__bf16)sC[8 + kc * 4 + e];
        af1[2 * e + 1] = (__bf16)cC[8 + kc * 4 + e];
      }
      bf16x8 b0 = *(const bf16x8*)(Bb + (kc * 2 + 0) * 512);
      bf16x8 b1 = *(const bf16x8*)(Bb + (kc * 2 + 1) * 512);
      acc00 = __builtin_amdgcn_mfma_f32_32x32x16_bf16(af0, b0, acc00, 0, 0, 0);
      acc10 = __builtin_amdgcn_mfma_f32_32x32x16_bf16(af1, b0, acc10, 0, 0, 0);
      acc01 = __builtin_amdgcn_mfma_f32_32x32x16_bf16(af0, b1, acc01, 0, 0, 0);
      acc11 = __builtin_amdgcn_mfma_f32_32x32x16_bf16(af1, b1, acc11, 0, 0, 0);
    }
    #pragma unroll
    for (int q = 0; q < 16; ++q) {    // prev <- freq 2p+2
      sP[q] = fmaf(Tch[q], sC[q], -sP[q]);
      cP[q] = fmaf(Tch[q], cC[q], -cP[q]);
    }

    // ---- second mode of pair: A from (sP,cP), B at +8192 elements
    #pragma unroll
    for (int kc = 0; kc < 2; ++kc) {
      bf16x8 af0, af1;
      #pragma unroll
      for (int e = 0; e < 4; ++e) {
        af0[2 * e]     = (__bf16)sP[kc * 4 + e];
        af0[2 * e + 1] = (__bf16)cP[kc * 4 + e];
        af1[2 * e]     = (__bf16)sP[8 + kc * 4 + e];
        af1[2 * e + 1] = (__bf16)cP[8 + kc * 4 + e];
      }
      bf16x8 b0 = *(const bf16x8*)(Bb + 8192 + (kc * 2 + 0) * 512);
      bf16x8 b1 = *(const bf16x8*)(Bb + 8192 + (kc * 2 + 1) * 512);
      acc00 = __builtin_amdgcn_mfma_f32_32x32x16_bf16(af0, b0, acc00, 0, 0, 0);
      acc10 = __builtin_amdgcn_mfma_f32_32x32x16_bf16(af1, b0, acc10, 0, 0, 0);
      acc01 = __builtin_amdgcn_mfma_f32_32x32x16_bf16(af0, b1, acc01, 0, 0, 0);
      acc11 = __builtin_amdgcn_mfma_f32_32x32x16_bf16(af1, b1, acc11, 0, 0, 0);
    }
    #pragma unroll
    for (int q = 0; q < 16; ++q) {    // cur <- freq 2p+3
      sC[q] = fmaf(Tch[q], sP[q], -sC[q]);
      cC[q] = fmaf(Tch[q], cP[q], -cC[q]);
    }
    __syncthreads();
  }

  // --- epilogue: quadrant exchange. Wave w owns quadrant q=w (t=q>>1,c=q&1).
  // LDS slot (q, contributor w): float at (q*4+w)*1024 + r*64 + lane
  // (lane stride 1 word -> conflict-free). Compile-time acc indices only.
  float* LX = (float*)&Bs[0][0];     // 64 KB scratch
  #pragma unroll
  for (int q = 0; q < 4; ++q) {
    // pick acc for quadrant q with compile-time indices
    const f32x16& a = (q == 0) ? acc00 : (q == 1) ? acc01
                     : (q == 2) ? acc10 : acc11;
    if (q != wave) {
      float* dst = LX + (q * 4 + wave) * 1024 + lane;
      #pragma unroll
      for (int r = 0; r < 16; ++r) dst[r * 64] = a[r];
    }
  }
  __syncthreads();

  // own quadrant partial, selected by wave-uniform branch (no dyn reg index)
  f32x16 sum;
  if      (wave == 0) sum = acc00;
  else if (wave == 1) sum = acc01;
  else if (wave == 2) sum = acc10;
  else                sum = acc11;

  #pragma unroll
  for (int w2 = 0; w2 < 4; ++w2) {
    if (w2 == wave) continue;
    const float* src = LX + (wave * 4 + w2) * 1024 + lane;
    #pragma unroll
    for (int r = 0; r < 16; ++r) sum[r] += src[r * 64];
  }

  int t_own = wave >> 1, c_own = wave & 1;
  int col = c_own * 32 + cl;
  float bv = bias[col] + bias2sum[col];
  float* orow = out + (size_t)(rowbase + t_own * 32) * 64;
  #pragma unroll
  for (int r = 0; r < 16; ++r) {
    int ro = (r & 3) + 8 * (r >> 2) + 4 * kq;
    orow[(size_t)ro * 64 + col] = sum[r] + bv;
  }
}

extern "C" void kernel_launch(void* const* d_in, const int* in_sizes, int n_in,
                              void* d_out, int out_size, void* d_ws, size_t ws_size,
                              hipStream_t stream) {
  const float* x      = (const float*)d_in[0];   // [65536, 64]
  const float* coeffs = (const float*)d_in[1];   // [64, 64, 65]
  const float* bias   = (const float*)d_in[2];   // [64]
  float* out = (float*)d_out;

  __bf16* Bp      = (__bf16*)d_ws;               // 512 KB
  float* bias2sum = (float*)((char*)d_ws + 512 * 1024);  // AFTER Bp

  int n_rows = in_sizes[0] / 64;                 // 65536

  hipMemsetAsync(bias2sum, 0, 64 * sizeof(float), stream);
  fkan_repack<<<(64 * 64 * 65 + 255) / 256, 256, 0, stream>>>(coeffs, Bp,
                                                              bias2sum);
  fkan_main<<<n_rows / 64, 256, 0, stream>>>(x, Bp, bias, bias2sum, out);
}